// Round 6
// baseline (79.471 us; speedup 1.0000x reference)
//
#include <hip/hip_runtime.h>

// ---------------------------------------------------------------------------
// QnnFormerVQC: 4-qubit VQC, B=262144, fp32 in / fp32 out.
// Round-5 fused kernel was <41us but latency-bound (246 dependent ds_bpermute
// in the U build + 512 v_readlane->v_fma hazard chains, at only 2 waves/SIMD).
// Round 6: two kernels, each with the right coefficient-delivery mechanism:
//   qnn_prep: 1 block/256 thr shuffle-circuit U builder (tiny code, ~2us),
//             writes 16x16 complex U to d_ws.
//   qnn_main: 1 elem/thread, 4 waves/SIMD. U consumed through a
//             readfirstlane-forced uniform pointer -> s_load rows into SGPRs,
//             matvec = v_fma with SGPR coefficient operands. No shuffles,
//             no readlanes, no vector loads of U.
// Circuit semantics = round-4/5 verified sequence (incl. the reference
// _apmcx quirk: swap amps 7<->15, NOT 14<->15).
// ---------------------------------------------------------------------------

// --- shuffle-gate helpers (prep): lane holds one amplitude of one column ---

__device__ __forceinline__ void g_rx(float& ar, float& ai, int amp, int m,
                                     float c, float s, int cmask) {
    const float br = __shfl_xor(ar, 1 << m, 64);
    const float bi = __shfl_xor(ai, 1 << m, 64);
    const float nr = c * ar + s * bi;
    const float ni = c * ai - s * br;
    const bool act = (amp & cmask) == cmask;
    ar = act ? nr : ar;
    ai = act ? ni : ai;
}

__device__ __forceinline__ void g_ry(float& ar, float& ai, int amp, int m,
                                     float c, float s) {
    const float br = __shfl_xor(ar, 1 << m, 64);
    const float bi = __shfl_xor(ai, 1 << m, 64);
    const float sp = ((amp >> m) & 1) ? s : -s;
    ar = c * ar + sp * br;
    ai = c * ai + sp * bi;
}

__device__ __forceinline__ void g_rz(float& ar, float& ai, int amp, int m,
                                     float c, float s) {
    const float p = ((amp >> m) & 1) ? s : -s;
    const float nr = c * ar - p * ai;
    const float ni = c * ai + p * ar;
    ar = nr; ai = ni;
}

__device__ __forceinline__ void g_h(float& ar, float& ai, int amp, int m) {
    const float R = 0.70710678118654752440f;
    const float br = __shfl_xor(ar, 1 << m, 64);
    const float bi = __shfl_xor(ai, 1 << m, 64);
    const bool hi = (amp >> m) & 1;
    ar = hi ? R * (br - ar) : R * (ar + br);
    ai = hi ? R * (bi - ai) : R * (ai + bi);
}

__device__ __forceinline__ void g_swap(float& ar, float& ai, int m, bool act) {
    const float br = __shfl_xor(ar, 1 << m, 64);
    const float bi = __shfl_xor(ai, 1 << m, 64);
    ar = act ? br : ar;
    ai = act ? bi : ai;
}

// 1 block, 256 threads: thread = (col = tid>>4, amp = tid&15).
__global__ void qnn_prep(const float* __restrict__ W, const float* __restrict__ E,
                         const float* __restrict__ G, const float* __restrict__ Bt,
                         float* __restrict__ Uout) {   // Ur[16][16] then Ui[16][16]
    __shared__ float2 cs[30];
    const int tid = threadIdx.x;

    if (tid < 30) {
        float th;
        if (tid < 12)      th = W[tid];
        else if (tid < 24) th = E[tid - 12];
        else if (tid < 27) th = G[tid - 24];
        else               th = Bt[tid - 27];
        float s, c;
        __sincosf(0.5f * th, &s, &c);
        cs[tid] = make_float2(c, s);
    }
    __syncthreads();

    const int col = tid >> 4;
    const int amp = tid & 15;
    float ar = (amp == col) ? 1.f : 0.f;
    float ai = 0.f;

    for (int l = 0; l < 3; ++l) {
#pragma unroll
        for (int q = 0; q < 4; ++q) {       // RX,RY,RZ with weights[l][q]
            const float2 cw = cs[l * 4 + q];
            g_rx(ar, ai, amp, 3 - q, cw.x, cw.y, 0);
            g_ry(ar, ai, amp, 3 - q, cw.x, cw.y);
            g_rz(ar, ai, amp, 3 - q, cw.x, cw.y);
        }
#pragma unroll
        for (int i = 0; i < 4; ++i) {       // CRX chain
            const float2 ce = cs[12 + l * 4 + i];
            g_rx(ar, ai, amp, 3 - ((i + 1) & 3), ce.x, ce.y, 1 << (3 - i));
        }
#pragma unroll
        for (int q = 0; q < 4; ++q) g_h(ar, ai, amp, 3 - q);     // H all
#pragma unroll
        for (int q = 0; q < 4; ++q) g_swap(ar, ai, 3 - q, true); // X all
        g_h(ar, ai, amp, 0);                                     // H(q3)
        g_swap(ar, ai, 3, (amp & 7) == 7);  // reference MCX: 7<->15
        g_h(ar, ai, amp, 0);                                     // H(q3)
#pragma unroll
        for (int q = 0; q < 4; ++q) g_swap(ar, ai, 3 - q, true); // X all
#pragma unroll
        for (int q = 0; q < 4; ++q) g_h(ar, ai, amp, 3 - q);     // H all
        {                                   // CX RZ(g) CX, i=0..2
            const float2 cg = cs[24 + l];
#pragma unroll
            for (int i = 0; i < 3; ++i) {
                const int cm = 1 << (3 - i);
                const int m  = 2 - i;
                g_swap(ar, ai, m, (amp & cm) == cm);
                g_rz(ar, ai, amp, m, cg.x, cg.y);
                g_swap(ar, ai, m, (amp & cm) == cm);
            }
        }
        {                                   // RX(beta) all
            const float2 cb = cs[27 + l];
#pragma unroll
            for (int q = 0; q < 4; ++q) g_rx(ar, ai, amp, 3 - q, cb.x, cb.y, 0);
        }
    }

    // lane (col,amp) holds U[amp][col]
    Uout[amp * 16 + col]       = ar;
    Uout[256 + amp * 16 + col] = ai;
}

__global__ __launch_bounds__(256, 4)
void qnn_main(const float* __restrict__ x, const float* __restrict__ Ug,
              float* __restrict__ out, int B) {
    const int b = blockIdx.x * 256 + threadIdx.x;
    if (b >= B) return;

    // Force-uniform pointer so U loads select the scalar (SMEM) path.
    const float* Us;
    {
        const unsigned long long up = (unsigned long long)(uintptr_t)Ug;
        const unsigned lo = __builtin_amdgcn_readfirstlane((unsigned)up);
        const unsigned hi = __builtin_amdgcn_readfirstlane((unsigned)(up >> 32));
        Us = (const float*)(uintptr_t)(((unsigned long long)hi << 32) | lo);
    }

    const float4 xv = reinterpret_cast<const float4*>(x)[b];
    float c0, s0, c1, s1, c2, s2, c3, s3;
    __sincosf(0.5f * xv.x, &s0, &c0);
    __sincosf(0.5f * xv.y, &s1, &c1);
    __sincosf(0.5f * xv.z, &s2, &c2);
    __sincosf(0.5f * xv.w, &s3, &c3);

    const float t01[4] = { c0 * c1, c0 * s1, s0 * c1, s0 * s1 };
    const float t23[4] = { c2 * c3, c2 * s3, s2 * c3, s2 * s3 };
    float v[16];
#pragma unroll
    for (int i = 0; i < 16; ++i) v[i] = t01[i >> 2] * t23[i & 3];

    // psi = U v — scalar coefficients, vector v.
    float pr[16], pi[16];
#pragma unroll
    for (int i = 0; i < 16; ++i) {
        float ur[16], ui[16];
#pragma unroll
        for (int j = 0; j < 16; ++j) {
            ur[j] = Us[i * 16 + j];
            ui[j] = Us[256 + i * 16 + j];
        }
        float ar = 0.f, ai = 0.f;
#pragma unroll
        for (int j = 0; j < 16; ++j) {
            ar = fmaf(ur[j], v[j], ar);
            ai = fmaf(ui[j], v[j], ai);
        }
        pr[i] = ar;
        pi[i] = ai;
    }

    float n[16];
#pragma unroll
    for (int i = 0; i < 16; ++i) n[i] = pr[i] * pr[i] + pi[i] * pi[i];

    float o[12];
#pragma unroll
    for (int q = 0; q < 4; ++q) {
        const int m = 3 - q;
        const int mask = 1 << m;
        float z = 0.f, cr = 0.f, ci = 0.f;
#pragma unroll
        for (int p = 0; p < 8; ++p) {
            const int i0 = ((p >> m) << (m + 1)) | (p & (mask - 1));
            const int i1 = i0 | mask;
            z  += n[i0] - n[i1];
            cr += pr[i0] * pr[i1] + pi[i0] * pi[i1];
            ci += pr[i0] * pi[i1] - pi[i0] * pr[i1];
        }
        o[q]     = z;
        o[4 + q] = 2.f * cr;
        o[8 + q] = 2.f * ci;
    }

    float4* op = reinterpret_cast<float4*>(out + (size_t)b * 12);
    op[0] = make_float4(o[0], o[1], o[2],  o[3]);
    op[1] = make_float4(o[4], o[5], o[6],  o[7]);
    op[2] = make_float4(o[8], o[9], o[10], o[11]);
}

extern "C" void kernel_launch(void* const* d_in, const int* in_sizes, int n_in,
                              void* d_out, int out_size, void* d_ws, size_t ws_size,
                              hipStream_t stream) {
    const float* x  = (const float*)d_in[0];
    const float* W  = (const float*)d_in[1];
    const float* E  = (const float*)d_in[2];
    const float* G  = (const float*)d_in[3];
    const float* Bt = (const float*)d_in[4];
    float* U   = (float*)d_ws;   // 512 floats
    float* out = (float*)d_out;
    const int B = in_sizes[0] / 4;   // 262144

    hipLaunchKernelGGL(qnn_prep, dim3(1), dim3(256), 0, stream, W, E, G, Bt, U);
    hipLaunchKernelGGL(qnn_main, dim3((B + 255) / 256), dim3(256), 0, stream,
                       x, U, out, B);
}